// Round 7
// baseline (135.344 us; speedup 1.0000x reference)
//
#include <hip/hip_runtime.h>
#include <math.h>

// grid: 800 blocks x 256 threads; each block owns 1024 contiguous rows,
// each thread owns 4 rows (t, t+256, t+512, t+768 within the chunk).
// prog 256 blocks (heads 0,1) | stck 128 (2,3,4) | locl 128 (5,6)
// heap 256 (7,8) | call 32 (9)
// ws: 1696 x u64 per-(block,head) packed winners, grouped per head.
__device__ __constant__ int HOFF[10] = {0, 256, 512, 640, 768, 896, 1024, 1152, 1408, 1664};
__device__ __constant__ int HCNT[10] = {256, 256, 128, 128, 128, 128, 128, 256, 256, 32};

static __device__ __forceinline__ unsigned int fkey(float f) {
  unsigned int u = __float_as_uint(f);
  return (u & 0x80000000u) ? ~u : (u | 0x80000000u);
}
static __device__ __forceinline__ float funkey(unsigned int k) {
  unsigned int u = (k & 0x80000000u) ? (k & 0x7fffffffu) : ~k;
  return __uint_as_float(u);
}
static __device__ __forceinline__ float dot4(float4 a, float4 b) {
  return a.x * b.x + a.y * b.y + a.z * b.z + a.w * b.w;
}

// ---- kernel 1: per-block prep (q + k_eff in LDS) + row-per-thread scan.
// Inner loop has ZERO cross-lane ops: full dot products accumulate in-thread;
// the only cross-lane reduce is the one-shot block endgame.
__global__ __launch_bounds__(256) void scan_kernel(
    const float* __restrict__ query,
    const float* __restrict__ prog, const float* __restrict__ stck,
    const float* __restrict__ locl, const float* __restrict__ heap,
    const float* __restrict__ call,
    const float* __restrict__ WQ, const float* __restrict__ bQ,
    const float* __restrict__ WK, float* __restrict__ ws)
{
  unsigned long long* res = (unsigned long long*)ws;
  int b = blockIdx.x, tid = threadIdx.x;

  const float* mem; int h0, nh, brank, off0, off1, off2;
  if (b < 256)      { mem = prog; h0 = 0; nh = 2; brank = b;       off0 = 0    + brank; off1 = 256 + brank;  off2 = 0; }
  else if (b < 384) { mem = stck; h0 = 2; nh = 3; brank = b - 256; off0 = 512  + brank; off1 = 640 + brank;  off2 = 768 + brank; }
  else if (b < 512) { mem = locl; h0 = 5; nh = 2; brank = b - 384; off0 = 896  + brank; off1 = 1024 + brank; off2 = 0; }
  else if (b < 768) { mem = heap; h0 = 7; nh = 2; brank = b - 512; off0 = 1152 + brank; off1 = 1408 + brank; off2 = 0; }
  else              { mem = call; h0 = 9; nh = 1; brank = b - 768; off0 = 1664 + brank; off1 = 0;            off2 = 0; }

  // ---- phase 0: q (serial 64-dot, bitwise-identical to reference) + k_eff in LDS
  __shared__ float qs[6];
  __shared__ float skeff[3][64];
  if (tid < 2 * nh) {
    const float* wq = WQ + (h0 * 2 + tid) * 64;
    float s = bQ[h0 * 2 + tid];
    for (int d = 0; d < 64; ++d) s += wq[d] * query[d];
    qs[tid] = s;
  }
  __syncthreads();
  if (tid < 192) {
    int hi = tid >> 6, d = tid & 63;
    float v = 0.f;
    if (hi < nh) {
      int h = h0 + hi;
      v = qs[2 * hi] * WK[(h * 2) * 64 + d] + qs[2 * hi + 1] * WK[(h * 2 + 1) * 64 + d];
    }
    skeff[hi][d] = v;
  }
  __syncthreads();

  // ---- phase 1: 4 rows per thread, j-outer loop over 16 float4 chunks.
  int base = brank * 1024;
  const float* r0 = mem + (size_t)(base + tid) * 64;          // row base+tid
  // rows base+tid+256 / +512 / +768 are fixed offsets from r0:
  //   +256*64, +512*64, +768*64 floats.
  float a0 = 0.f, a1 = 0.f, a2 = 0.f, a3 = 0.f;   // head h0   x 4 rows
  float b0 = 0.f, b1 = 0.f, b2 = 0.f, b3 = 0.f;   // head h0+1 x 4 rows
  float c0 = 0.f, c1 = 0.f, c2 = 0.f, c3 = 0.f;   // head h0+2 x 4 rows

#pragma unroll
  for (int j = 0; j < 16; ++j) {
    float4 kA = ((const float4*)skeff[0])[j];   // wave-uniform LDS broadcast
    float4 kB = ((const float4*)skeff[1])[j];
    float4 kC = ((const float4*)skeff[2])[j];
    float4 v0 = *(const float4*)(r0 + j * 4);
    float4 v1 = *(const float4*)(r0 + 256 * 64 + j * 4);
    float4 v2 = *(const float4*)(r0 + 512 * 64 + j * 4);
    float4 v3 = *(const float4*)(r0 + 768 * 64 + j * 4);

    a0 += dot4(v0, kA); a1 += dot4(v1, kA); a2 += dot4(v2, kA); a3 += dot4(v3, kA);
    b0 += dot4(v0, kB); b1 += dot4(v1, kB); b2 += dot4(v2, kB); b3 += dot4(v3, kB);
    c0 += dot4(v0, kC); c1 += dot4(v1, kC); c2 += dot4(v2, kC); c3 += dot4(v3, kC);
  }

  // thread-local argmax per head (rows in ascending index order; strict > keeps first)
  int rI = base + tid;
  float bsA = a0; int biA = rI;
  if (a1 > bsA) { bsA = a1; biA = rI + 256; }
  if (a2 > bsA) { bsA = a2; biA = rI + 512; }
  if (a3 > bsA) { bsA = a3; biA = rI + 768; }
  float bsB = b0; int biB = rI;
  if (b1 > bsB) { bsB = b1; biB = rI + 256; }
  if (b2 > bsB) { bsB = b2; biB = rI + 512; }
  if (b3 > bsB) { bsB = b3; biB = rI + 768; }
  float bsC = c0; int biC = rI;
  if (c1 > bsC) { bsC = c1; biC = rI + 256; }
  if (c2 > bsC) { bsC = c2; biC = rI + 512; }
  if (c3 > bsC) { bsC = c3; biC = rI + 768; }

  // ---- phase 2: one-shot block reduce (packed u64), non-atomic winner store
  unsigned long long p0 = ((unsigned long long)fkey(bsA) << 32) | (unsigned long long)(0xFFFFFFFFu - (unsigned)biA);
  unsigned long long p1 = ((unsigned long long)fkey(bsB) << 32) | (unsigned long long)(0xFFFFFFFFu - (unsigned)biB);
  unsigned long long p2 = ((unsigned long long)fkey(bsC) << 32) | (unsigned long long)(0xFFFFFFFFu - (unsigned)biC);
#pragma unroll
  for (int m = 1; m < 64; m <<= 1) {
    unsigned long long t;
    t = __shfl_xor(p0, m); if (t > p0) p0 = t;
    t = __shfl_xor(p1, m); if (t > p1) p1 = t;
    t = __shfl_xor(p2, m); if (t > p2) p2 = t;
  }
  __shared__ unsigned long long red[3][4];
  int wv = tid >> 6;
  if ((tid & 63) == 0) { red[0][wv] = p0; red[1][wv] = p1; red[2][wv] = p2; }
  __syncthreads();
  if (tid == 0) {
    unsigned long long m0 = red[0][0], m1 = red[1][0], m2 = red[2][0];
#pragma unroll
    for (int w = 1; w < 4; ++w) {
      if (red[0][w] > m0) m0 = red[0][w];
      if (red[1][w] > m1) m1 = red[1][w];
      if (red[2][w] > m2) m2 = red[2][w];
    }
    res[off0] = m0;
    if (nh > 1) res[off1] = m1;
    if (nh > 2) res[off2] = m2;
  }
}

// ---- kernel 2: reduce per-head winner arrays (1 wave per head), then 12 value dots.
__global__ __launch_bounds__(640) void epi_kernel(
    const float* __restrict__ prog, const float* __restrict__ stck,
    const float* __restrict__ locl, const float* __restrict__ heap,
    const float* __restrict__ call,
    const float* __restrict__ WV1, const float* __restrict__ WVc,
    const float* __restrict__ ws, float* __restrict__ out) {
  const unsigned long long* res = (const unsigned long long*)ws;
  __shared__ int sidx[10];
  int tid = threadIdx.x;
  int w = tid >> 6, lane = tid & 63;
  if (w < 10) {
    const unsigned long long* basep = res + HOFF[w];
    int n = HCNT[w];
    unsigned long long m = 0ull;
    for (int i = lane; i < n; i += 64) {
      unsigned long long v = basep[i];
      if (v > m) m = v;
    }
#pragma unroll
    for (int s = 1; s < 64; s <<= 1) {
      unsigned long long t = __shfl_xor(m, s);
      if (t > m) m = t;
    }
    if (lane == 0) {
      unsigned int key = (unsigned int)(m >> 32);
      int idx = (int)(0xFFFFFFFFu - (unsigned int)(m & 0xFFFFFFFFull));
      sidx[w] = idx;
      out[12 + w] = funkey(key);      // best_scores
      out[22 + w] = (float)idx;       // best_idx (as f32)
    }
  }
  __syncthreads();
  int p = tid >> 4, l = tid & 15;
  if (p < 12) {
    int hh = (p < 9) ? p : 9;
    const float* wrow = (p < 9) ? (WV1 + p * 64) : (WVc + (p - 9) * 64);
    const float* vmem;
    if (hh < 2) vmem = prog;
    else if (hh < 5) vmem = stck;
    else if (hh < 7) vmem = locl;
    else if (hh < 9) vmem = heap;
    else vmem = call;
    const float* row = vmem + (size_t)sidx[hh] * 64;
    float s = 0.f;
#pragma unroll
    for (int j = 0; j < 4; ++j) s += wrow[l * 4 + j] * row[l * 4 + j];
#pragma unroll
    for (int m2 = 1; m2 < 16; m2 <<= 1) s += __shfl_xor(s, m2);
    if (l == 0) out[p] = s;
  }
}

extern "C" void kernel_launch(void* const* d_in, const int* in_sizes, int n_in,
                              void* d_out, int out_size, void* d_ws, size_t ws_size,
                              hipStream_t stream) {
  const float* query = (const float*)d_in[0];
  const float* prog  = (const float*)d_in[1];
  const float* stck  = (const float*)d_in[2];
  const float* locl  = (const float*)d_in[3];
  const float* heap  = (const float*)d_in[4];
  const float* call  = (const float*)d_in[5];
  const float* WQ    = (const float*)d_in[6];
  const float* bQ    = (const float*)d_in[7];
  const float* WK    = (const float*)d_in[8];
  const float* WV1   = (const float*)d_in[9];
  const float* WVc   = (const float*)d_in[10];
  float* ws  = (float*)d_ws;
  float* out = (float*)d_out;

  hipLaunchKernelGGL(scan_kernel, dim3(800), dim3(256), 0, stream,
                     query, prog, stck, locl, heap, call, WQ, bQ, WK, ws);
  hipLaunchKernelGGL(epi_kernel, dim3(1), dim3(640), 0, stream,
                     prog, stck, locl, heap, call, WV1, WVc, ws, out);
}

// Round 8
// 50.958 us; speedup vs baseline: 2.6560x; 2.6560x over previous
//
#include <hip/hip_runtime.h>
#include <math.h>

// grid layout: 1600 blocks x 256 threads, each block owns a contiguous 512-row chunk.
// prog 512 blocks (heads 0,1) | stck 256 (2,3,4) | locl 256 (5,6)
// heap 512 (7,8) | call 64 (9)
// ws: 3392 x u64 per-(block,head) packed winners, grouped per head.
__device__ __constant__ int HOFF[10] = {0, 512, 1024, 1280, 1536, 1792, 2048, 2304, 2816, 3328};
__device__ __constant__ int HCNT[10] = {512, 512, 256, 256, 256, 256, 256, 512, 512, 64};

static __device__ __forceinline__ unsigned int fkey(float f) {
  unsigned int u = __float_as_uint(f);
  return (u & 0x80000000u) ? ~u : (u | 0x80000000u);
}
static __device__ __forceinline__ float funkey(unsigned int k) {
  unsigned int u = (k & 0x80000000u) ? (k & 0x7fffffffu) : ~k;
  return __uint_as_float(u);
}
static __device__ __forceinline__ float dot4(float4 a, float4 b) {
  return a.x * b.x + a.y * b.y + a.z * b.z + a.w * b.w;
}

// ---- kernel 1: per-block prep (q + k_eff in LDS) + scan with register
// double-buffer prefetch: loads of iteration it+1 are issued before the
// compute (incl. dependent shfl chains) of iteration it -> continuous MLP.
__global__ __launch_bounds__(256) void scan_kernel(
    const float* __restrict__ query,
    const float* __restrict__ prog, const float* __restrict__ stck,
    const float* __restrict__ locl, const float* __restrict__ heap,
    const float* __restrict__ call,
    const float* __restrict__ WQ, const float* __restrict__ bQ,
    const float* __restrict__ WK, float* __restrict__ ws)
{
  unsigned long long* res = (unsigned long long*)ws;
  int b = blockIdx.x, tid = threadIdx.x;

  const float* mem; int h0, nh, brank, off0, off1, off2;
  if (b < 512)       { mem = prog; h0 = 0; nh = 2; brank = b;        off0 = 0    + brank; off1 = 512  + brank; off2 = 0; }
  else if (b < 768)  { mem = stck; h0 = 2; nh = 3; brank = b - 512;  off0 = 1024 + brank; off1 = 1280 + brank; off2 = 1536 + brank; }
  else if (b < 1024) { mem = locl; h0 = 5; nh = 2; brank = b - 768;  off0 = 1792 + brank; off1 = 2048 + brank; off2 = 0; }
  else if (b < 1536) { mem = heap; h0 = 7; nh = 2; brank = b - 1024; off0 = 2304 + brank; off1 = 2816 + brank; off2 = 0; }
  else               { mem = call; h0 = 9; nh = 1; brank = b - 1536; off0 = 3328 + brank; off1 = 0;            off2 = 0; }

  // ---- phase 0: q (serial 64-dot, bitwise-identical to reference) + k_eff in LDS
  __shared__ float qs[6];
  __shared__ float skeff[3][64];
  if (tid < 2 * nh) {
    const float* wq = WQ + (h0 * 2 + tid) * 64;
    float s = bQ[h0 * 2 + tid];
    for (int d = 0; d < 64; ++d) s += wq[d] * query[d];
    qs[tid] = s;
  }
  __syncthreads();
  if (tid < 192) {
    int hi = tid >> 6, d = tid & 63;
    float v = 0.f;
    if (hi < nh) {
      int h = h0 + hi;
      v = qs[2 * hi] * WK[(h * 2) * 64 + d] + qs[2 * hi + 1] * WK[(h * 2 + 1) * 64 + d];
    }
    skeff[hi][d] = v;
  }
  __syncthreads();

  // ---- phase 1: 512 rows, 8 iters x 64 rows; 4 lanes/row (R5 layout).
  int lane4 = tid & 3, rsub = tid >> 2;

  float4 ka[4], kb[4], kc[4];
#pragma unroll
  for (int j = 0; j < 4; ++j) {
    ka[j] = ((const float4*)skeff[0])[j * 4 + lane4];
    kb[j] = ((const float4*)skeff[1])[j * 4 + lane4];
    kc[j] = ((const float4*)skeff[2])[j * 4 + lane4];
  }

  float bsA = -INFINITY, bsB = -INFINITY, bsC = -INFINITY;
  int biA = 0, biB = 0, biC = 0;
  int base = brank * 512;
  const float* rowbase = mem + (size_t)(base + rsub) * 64 + lane4 * 4;
  // iteration it reads row base + it*64 + rsub -> float offset it*4096 from rowbase

  float4 n0 = *(const float4*)(rowbase +  0);
  float4 n1 = *(const float4*)(rowbase + 16);
  float4 n2 = *(const float4*)(rowbase + 32);
  float4 n3 = *(const float4*)(rowbase + 48);

#pragma unroll
  for (int it = 0; it < 8; ++it) {
    float4 v0 = n0, v1 = n1, v2 = n2, v3 = n3;
    if (it < 7) {
      const float* p = rowbase + (size_t)(it + 1) * 4096;
      n0 = *(const float4*)(p +  0);
      n1 = *(const float4*)(p + 16);
      n2 = *(const float4*)(p + 32);
      n3 = *(const float4*)(p + 48);
    }

    float sA = dot4(v0, ka[0]) + dot4(v1, ka[1]) + dot4(v2, ka[2]) + dot4(v3, ka[3]);
    float sB = dot4(v0, kb[0]) + dot4(v1, kb[1]) + dot4(v2, kb[2]) + dot4(v3, kb[3]);
    float sC = dot4(v0, kc[0]) + dot4(v1, kc[1]) + dot4(v2, kc[2]) + dot4(v3, kc[3]);

    sA += __shfl_xor(sA, 1); sA += __shfl_xor(sA, 2);
    sB += __shfl_xor(sB, 1); sB += __shfl_xor(sB, 2);
    sC += __shfl_xor(sC, 1); sC += __shfl_xor(sC, 2);

    int r = base + it * 64 + rsub;
    if (sA > bsA) { bsA = sA; biA = r; }
    if (sB > bsB) { bsB = sB; biB = r; }
    if (sC > bsC) { bsC = sC; biC = r; }
  }

  // ---- phase 2: block reduce, non-atomic store of packed (key, ~idx)
  unsigned long long p0 = ((unsigned long long)fkey(bsA) << 32) | (unsigned long long)(0xFFFFFFFFu - (unsigned)biA);
  unsigned long long p1 = ((unsigned long long)fkey(bsB) << 32) | (unsigned long long)(0xFFFFFFFFu - (unsigned)biB);
  unsigned long long p2 = ((unsigned long long)fkey(bsC) << 32) | (unsigned long long)(0xFFFFFFFFu - (unsigned)biC);
#pragma unroll
  for (int m = 4; m < 64; m <<= 1) {   // lanes within 4-group already identical
    unsigned long long t;
    t = __shfl_xor(p0, m); if (t > p0) p0 = t;
    t = __shfl_xor(p1, m); if (t > p1) p1 = t;
    t = __shfl_xor(p2, m); if (t > p2) p2 = t;
  }
  __shared__ unsigned long long red[3][4];
  int wv = tid >> 6;
  if ((tid & 63) == 0) { red[0][wv] = p0; red[1][wv] = p1; red[2][wv] = p2; }
  __syncthreads();
  if (tid == 0) {
    unsigned long long m0 = red[0][0], m1 = red[1][0], m2 = red[2][0];
#pragma unroll
    for (int w = 1; w < 4; ++w) {
      if (red[0][w] > m0) m0 = red[0][w];
      if (red[1][w] > m1) m1 = red[1][w];
      if (red[2][w] > m2) m2 = red[2][w];
    }
    res[off0] = m0;
    if (nh > 1) res[off1] = m1;
    if (nh > 2) res[off2] = m2;
  }
}

// ---- kernel 2: reduce per-head winner arrays (1 wave per head), then 12 value dots.
__global__ __launch_bounds__(640) void epi_kernel(
    const float* __restrict__ prog, const float* __restrict__ stck,
    const float* __restrict__ locl, const float* __restrict__ heap,
    const float* __restrict__ call,
    const float* __restrict__ WV1, const float* __restrict__ WVc,
    const float* __restrict__ ws, float* __restrict__ out) {
  const unsigned long long* res = (const unsigned long long*)ws;
  __shared__ int sidx[10];
  int tid = threadIdx.x;
  int w = tid >> 6, lane = tid & 63;
  if (w < 10) {
    const unsigned long long* basep = res + HOFF[w];
    int n = HCNT[w];
    unsigned long long m = 0ull;
    for (int i = lane; i < n; i += 64) {
      unsigned long long v = basep[i];
      if (v > m) m = v;
    }
#pragma unroll
    for (int s = 1; s < 64; s <<= 1) {
      unsigned long long t = __shfl_xor(m, s);
      if (t > m) m = t;
    }
    if (lane == 0) {
      unsigned int key = (unsigned int)(m >> 32);
      int idx = (int)(0xFFFFFFFFu - (unsigned int)(m & 0xFFFFFFFFull));
      sidx[w] = idx;
      out[12 + w] = funkey(key);      // best_scores
      out[22 + w] = (float)idx;       // best_idx (as f32)
    }
  }
  __syncthreads();
  int p = tid >> 4, l = tid & 15;
  if (p < 12) {
    int hh = (p < 9) ? p : 9;
    const float* wrow = (p < 9) ? (WV1 + p * 64) : (WVc + (p - 9) * 64);
    const float* vmem;
    if (hh < 2) vmem = prog;
    else if (hh < 5) vmem = stck;
    else if (hh < 7) vmem = locl;
    else if (hh < 9) vmem = heap;
    else vmem = call;
    const float* row = vmem + (size_t)sidx[hh] * 64;
    float s = 0.f;
#pragma unroll
    for (int j = 0; j < 4; ++j) s += wrow[l * 4 + j] * row[l * 4 + j];
#pragma unroll
    for (int m2 = 1; m2 < 16; m2 <<= 1) s += __shfl_xor(s, m2);
    if (l == 0) out[p] = s;
  }
}

extern "C" void kernel_launch(void* const* d_in, const int* in_sizes, int n_in,
                              void* d_out, int out_size, void* d_ws, size_t ws_size,
                              hipStream_t stream) {
  const float* query = (const float*)d_in[0];
  const float* prog  = (const float*)d_in[1];
  const float* stck  = (const float*)d_in[2];
  const float* locl  = (const float*)d_in[3];
  const float* heap  = (const float*)d_in[4];
  const float* call  = (const float*)d_in[5];
  const float* WQ    = (const float*)d_in[6];
  const float* bQ    = (const float*)d_in[7];
  const float* WK    = (const float*)d_in[8];
  const float* WV1   = (const float*)d_in[9];
  const float* WVc   = (const float*)d_in[10];
  float* ws  = (float*)d_ws;
  float* out = (float*)d_out;

  hipLaunchKernelGGL(scan_kernel, dim3(1600), dim3(256), 0, stream,
                     query, prog, stck, locl, heap, call, WQ, bQ, WK, ws);
  hipLaunchKernelGGL(epi_kernel, dim3(1), dim3(640), 0, stream,
                     prog, stck, locl, heap, call, WV1, WVc, ws, out);
}

// Round 9
// 49.196 us; speedup vs baseline: 2.7511x; 1.0358x over previous
//
#include <hip/hip_runtime.h>
#include <math.h>

// grid layout: 1600 blocks x 256 threads, each block owns a contiguous 512-row chunk.
// prog 512 blocks (heads 0,1) | stck 256 (2,3,4) | locl 256 (5,6)
// heap 512 (7,8) | call 64 (9)
// ws: 3392 x u64 per-(block,head) packed winners, grouped per head.
// Cache policy: prog+heap (128 MB) loaded NON-TEMPORAL (bypass L2/L3 allocate)
// so stck+locl+call (72 MB) stay L3-resident across replays.
__device__ __constant__ int HOFF[10] = {0, 512, 1024, 1280, 1536, 1792, 2048, 2304, 2816, 3328};
__device__ __constant__ int HCNT[10] = {512, 512, 256, 256, 256, 256, 256, 512, 512, 64};

typedef float f32x4 __attribute__((ext_vector_type(4)));

static __device__ __forceinline__ unsigned int fkey(float f) {
  unsigned int u = __float_as_uint(f);
  return (u & 0x80000000u) ? ~u : (u | 0x80000000u);
}
static __device__ __forceinline__ float funkey(unsigned int k) {
  unsigned int u = (k & 0x80000000u) ? (k & 0x7fffffffu) : ~k;
  return __uint_as_float(u);
}
static __device__ __forceinline__ float dot4(float4 a, float4 b) {
  return a.x * b.x + a.y * b.y + a.z * b.z + a.w * b.w;
}

template <bool NT>
static __device__ __forceinline__ float4 ld4(const float* p) {
  if constexpr (NT) {
    f32x4 v = __builtin_nontemporal_load((const f32x4*)p);
    return make_float4(v.x, v.y, v.z, v.w);
  } else {
    return *(const float4*)p;
  }
}

// scan 512 rows (8 iters x 64 rows), 4 lanes per row; template picks cache policy.
template <bool NT>
static __device__ __forceinline__ void scan_rows(
    const float* __restrict__ mem, int base, int rsub, int lane4,
    const float4* ka, const float4* kb, const float4* kc,
    float& bsA, int& biA, float& bsB, int& biB, float& bsC, int& biC)
{
#pragma unroll 2
  for (int it = 0; it < 8; ++it) {
    int r = base + it * 64 + rsub;
    const float* rowp = mem + (size_t)r * 64 + lane4 * 4;
    float4 v0 = ld4<NT>(rowp +  0);
    float4 v1 = ld4<NT>(rowp + 16);
    float4 v2 = ld4<NT>(rowp + 32);
    float4 v3 = ld4<NT>(rowp + 48);

    float sA = dot4(v0, ka[0]) + dot4(v1, ka[1]) + dot4(v2, ka[2]) + dot4(v3, ka[3]);
    float sB = dot4(v0, kb[0]) + dot4(v1, kb[1]) + dot4(v2, kb[2]) + dot4(v3, kb[3]);
    float sC = dot4(v0, kc[0]) + dot4(v1, kc[1]) + dot4(v2, kc[2]) + dot4(v3, kc[3]);

    sA += __shfl_xor(sA, 1); sA += __shfl_xor(sA, 2);
    sB += __shfl_xor(sB, 1); sB += __shfl_xor(sB, 2);
    sC += __shfl_xor(sC, 1); sC += __shfl_xor(sC, 2);

    if (sA > bsA) { bsA = sA; biA = r; }
    if (sB > bsB) { bsB = sB; biB = r; }
    if (sC > bsC) { bsC = sC; biC = r; }
  }
}

// ---- kernel 1: per-block prep (q + k_eff in LDS) + scan + block-winner store.
__global__ __launch_bounds__(256) void scan_kernel(
    const float* __restrict__ query,
    const float* __restrict__ prog, const float* __restrict__ stck,
    const float* __restrict__ locl, const float* __restrict__ heap,
    const float* __restrict__ call,
    const float* __restrict__ WQ, const float* __restrict__ bQ,
    const float* __restrict__ WK, float* __restrict__ ws)
{
  unsigned long long* res = (unsigned long long*)ws;
  int b = blockIdx.x, tid = threadIdx.x;

  const float* mem; int h0, nh, brank, off0, off1, off2; bool nt;
  if (b < 512)       { mem = prog; h0 = 0; nh = 2; brank = b;        off0 = 0    + brank; off1 = 512  + brank; off2 = 0;            nt = true;  }
  else if (b < 768)  { mem = stck; h0 = 2; nh = 3; brank = b - 512;  off0 = 1024 + brank; off1 = 1280 + brank; off2 = 1536 + brank; nt = false; }
  else if (b < 1024) { mem = locl; h0 = 5; nh = 2; brank = b - 768;  off0 = 1792 + brank; off1 = 2048 + brank; off2 = 0;            nt = false; }
  else if (b < 1536) { mem = heap; h0 = 7; nh = 2; brank = b - 1024; off0 = 2304 + brank; off1 = 2816 + brank; off2 = 0;            nt = true;  }
  else               { mem = call; h0 = 9; nh = 1; brank = b - 1536; off0 = 3328 + brank; off1 = 0;            off2 = 0;            nt = false; }

  // ---- phase 0: q (serial 64-dot, bitwise-identical to reference) + k_eff in LDS
  __shared__ float qs[6];
  __shared__ float skeff[3][64];
  if (tid < 2 * nh) {
    const float* wq = WQ + (h0 * 2 + tid) * 64;
    float s = bQ[h0 * 2 + tid];
    for (int d = 0; d < 64; ++d) s += wq[d] * query[d];
    qs[tid] = s;
  }
  __syncthreads();
  if (tid < 192) {
    int hi = tid >> 6, d = tid & 63;
    float v = 0.f;
    if (hi < nh) {
      int h = h0 + hi;
      v = qs[2 * hi] * WK[(h * 2) * 64 + d] + qs[2 * hi + 1] * WK[(h * 2 + 1) * 64 + d];
    }
    skeff[hi][d] = v;
  }
  __syncthreads();

  // ---- phase 1: scan with per-bank cache policy
  int lane4 = tid & 3, rsub = tid >> 2;

  float4 ka[4], kb[4], kc[4];
#pragma unroll
  for (int j = 0; j < 4; ++j) {
    ka[j] = ((const float4*)skeff[0])[j * 4 + lane4];
    kb[j] = ((const float4*)skeff[1])[j * 4 + lane4];
    kc[j] = ((const float4*)skeff[2])[j * 4 + lane4];
  }

  float bsA = -INFINITY, bsB = -INFINITY, bsC = -INFINITY;
  int biA = 0, biB = 0, biC = 0;
  int base = brank * 512;
  if (nt) scan_rows<true >(mem, base, rsub, lane4, ka, kb, kc, bsA, biA, bsB, biB, bsC, biC);
  else    scan_rows<false>(mem, base, rsub, lane4, ka, kb, kc, bsA, biA, bsB, biB, bsC, biC);

  // ---- phase 2: block reduce, non-atomic store of packed (key, ~idx)
  unsigned long long p0 = ((unsigned long long)fkey(bsA) << 32) | (unsigned long long)(0xFFFFFFFFu - (unsigned)biA);
  unsigned long long p1 = ((unsigned long long)fkey(bsB) << 32) | (unsigned long long)(0xFFFFFFFFu - (unsigned)biB);
  unsigned long long p2 = ((unsigned long long)fkey(bsC) << 32) | (unsigned long long)(0xFFFFFFFFu - (unsigned)biC);
#pragma unroll
  for (int m = 4; m < 64; m <<= 1) {   // lanes within 4-group already identical
    unsigned long long t;
    t = __shfl_xor(p0, m); if (t > p0) p0 = t;
    t = __shfl_xor(p1, m); if (t > p1) p1 = t;
    t = __shfl_xor(p2, m); if (t > p2) p2 = t;
  }
  __shared__ unsigned long long red[3][4];
  int wv = tid >> 6;
  if ((tid & 63) == 0) { red[0][wv] = p0; red[1][wv] = p1; red[2][wv] = p2; }
  __syncthreads();
  if (tid == 0) {
    unsigned long long m0 = red[0][0], m1 = red[1][0], m2 = red[2][0];
#pragma unroll
    for (int w = 1; w < 4; ++w) {
      if (red[0][w] > m0) m0 = red[0][w];
      if (red[1][w] > m1) m1 = red[1][w];
      if (red[2][w] > m2) m2 = red[2][w];
    }
    res[off0] = m0;
    if (nh > 1) res[off1] = m1;
    if (nh > 2) res[off2] = m2;
  }
}

// ---- kernel 2: reduce per-head winner arrays (1 wave per head), then 12 value dots.
__global__ __launch_bounds__(640) void epi_kernel(
    const float* __restrict__ prog, const float* __restrict__ stck,
    const float* __restrict__ locl, const float* __restrict__ heap,
    const float* __restrict__ call,
    const float* __restrict__ WV1, const float* __restrict__ WVc,
    const float* __restrict__ ws, float* __restrict__ out) {
  const unsigned long long* res = (const unsigned long long*)ws;
  __shared__ int sidx[10];
  int tid = threadIdx.x;
  int w = tid >> 6, lane = tid & 63;
  if (w < 10) {
    const unsigned long long* basep = res + HOFF[w];
    int n = HCNT[w];
    unsigned long long m = 0ull;
    for (int i = lane; i < n; i += 64) {
      unsigned long long v = basep[i];
      if (v > m) m = v;
    }
#pragma unroll
    for (int s = 1; s < 64; s <<= 1) {
      unsigned long long t = __shfl_xor(m, s);
      if (t > m) m = t;
    }
    if (lane == 0) {
      unsigned int key = (unsigned int)(m >> 32);
      int idx = (int)(0xFFFFFFFFu - (unsigned int)(m & 0xFFFFFFFFull));
      sidx[w] = idx;
      out[12 + w] = funkey(key);      // best_scores
      out[22 + w] = (float)idx;       // best_idx (as f32)
    }
  }
  __syncthreads();
  int p = tid >> 4, l = tid & 15;
  if (p < 12) {
    int hh = (p < 9) ? p : 9;
    const float* wrow = (p < 9) ? (WV1 + p * 64) : (WVc + (p - 9) * 64);
    const float* vmem;
    if (hh < 2) vmem = prog;
    else if (hh < 5) vmem = stck;
    else if (hh < 7) vmem = locl;
    else if (hh < 9) vmem = heap;
    else vmem = call;
    const float* row = vmem + (size_t)sidx[hh] * 64;
    float s = 0.f;
#pragma unroll
    for (int j = 0; j < 4; ++j) s += wrow[l * 4 + j] * row[l * 4 + j];
#pragma unroll
    for (int m2 = 1; m2 < 16; m2 <<= 1) s += __shfl_xor(s, m2);
    if (l == 0) out[p] = s;
  }
}

extern "C" void kernel_launch(void* const* d_in, const int* in_sizes, int n_in,
                              void* d_out, int out_size, void* d_ws, size_t ws_size,
                              hipStream_t stream) {
  const float* query = (const float*)d_in[0];
  const float* prog  = (const float*)d_in[1];
  const float* stck  = (const float*)d_in[2];
  const float* locl  = (const float*)d_in[3];
  const float* heap  = (const float*)d_in[4];
  const float* call  = (const float*)d_in[5];
  const float* WQ    = (const float*)d_in[6];
  const float* bQ    = (const float*)d_in[7];
  const float* WK    = (const float*)d_in[8];
  const float* WV1   = (const float*)d_in[9];
  const float* WVc   = (const float*)d_in[10];
  float* ws  = (float*)d_ws;
  float* out = (float*)d_out;

  hipLaunchKernelGGL(scan_kernel, dim3(1600), dim3(256), 0, stream,
                     query, prog, stck, locl, heap, call, WQ, bQ, WK, ws);
  hipLaunchKernelGGL(epi_kernel, dim3(1), dim3(640), 0, stream,
                     prog, stck, locl, heap, call, WV1, WVc, ws, out);
}